// Round 6
// baseline (231.331 us; speedup 1.0000x reference)
//
#include <hip/hip_runtime.h>
#include <hip/hip_bf16.h>
#include <math.h>

// GAT forward, N=4096, nfeat=512, nhid=64, nheads=8, nout=56, f32 in/out.
// R21 vs R20 (R20: 205.6us; attn 59.7us). R20's A/B proved each barrier
// phase costs ~1200 cyc (halving barriers saved 600 cyc/tile exactly);
// 16 barriers + 4-wave lockstep convoying still dominate attn.
//  - attn11: NO LDS, NO BARRIERS. h-image re-laid out FRAGMENT-MAJOR:
//    per j-tile, 8 fragments (fr = ks*4+nt) of 1KB; lane l's bf16x8 at
//    fr*512 + l*8 shorts. A fragment load = ONE perfectly-coalesced
//    global_load_dwordx4 (1KB/wave, L1/L2-resident: images total 4MB).
//    Waves free-run; eb(ks0)/adj prefetched 1 tile ahead in registers,
//    bh + eb(ks1) loaded at tile top (covered by pack + wave stagger).
//    #pragma unroll 2 removes rotation copies. Same op order as R20 ->
//    bit-identical output (absmax must be exactly 1.2207e-4).
//  - gemm_fused / mid: ONLY the image-emit offset formula changes
//    (swizzled -> frag-major). Values/packs identical.
//  - prep (xh/wth for gemm LDS path) / fink2 / workspace: byte-identical.

#define GN 4096
#define GNH 8
#define LOG2E 1.4426950408889634f

typedef __bf16 bf16x8 __attribute__((ext_vector_type(8)));
typedef float f32x4 __attribute__((ext_vector_type(4)));

#if defined(__has_builtin)
#if __has_builtin(__builtin_amdgcn_exp2f)
#define FAST_EXP2(x) __builtin_amdgcn_exp2f(x)
#endif
#if __has_builtin(__builtin_amdgcn_perm)
#define FAST_PERM(a, b, s) __builtin_amdgcn_perm((a), (b), (s))
#endif
#endif
#ifndef FAST_EXP2
#define FAST_EXP2(x) __expf((x)*0.6931471805599453f)
#endif
#ifndef FAST_PERM
__device__ inline unsigned FAST_PERM(unsigned a, unsigned b, unsigned) {
    return (a & 0xFFFF0000u) | (b >> 16);
}
#endif

// round-half-up hi only, packed pair: low 16 = v0's bf16, high 16 = v1's
__device__ inline unsigned hi_pack2(float w0, float w1) {
    unsigned u0 = __float_as_uint(w0) + 0x8000u;
    unsigned u1 = __float_as_uint(w1) + 0x8000u;
    return FAST_PERM(u1, u0, 0x07060302u);
}

// Fused prep:
//  [0,16384)      pack_adj  (bitmask)
//  [16384,17408)  conv_x    -> swizzled x image (hi only), tiles [itile*8+kt]
//  [17408,17472)  conv_wt   -> swizzled W^T image (hi only), tiles [head*8+kt]
// Image unit (m, c) at shorts offset m*64 + ((c^(m&7))*8), elems k = c*8+q.
__global__ __launch_bounds__(256) void prep(const int* __restrict__ adj,
                                            const float* __restrict__ x,
                                            const float* __restrict__ Ws,
                                            unsigned long long* __restrict__ adjb,
                                            unsigned short* __restrict__ xh,
                                            unsigned short* __restrict__ wth) {
    const int b = blockIdx.x;
    const int tid = threadIdx.x;
    if (b < 16384) {
        const int wv = tid >> 6, lane = tid & 63;
        const size_t ebase = ((size_t)b * 4 + wv) * 256;
        unsigned long long m[4];
        #pragma unroll
        for (int e = 0; e < 4; ++e)
            m[e] = __ballot(adj[ebase + e * 64 + lane] > 0);
        if (lane == 0) {
            #pragma unroll
            for (int e = 0; e < 4; ++e) adjb[(ebase >> 6) + e] = m[e];
        }
    } else if (b < 17408) {
        int gid = (b - 16384) * 256 + tid;           // over 4096 rows x 64 units
        int i = gid >> 6, c64 = gid & 63;
        const float* xp = x + (size_t)i * 512 + c64 * 8;
        float4 a = *(const float4*)xp;
        float4 v = *(const float4*)(xp + 4);
        unsigned hp[4];
        hp[0] = hi_pack2(a.x, a.y);
        hp[1] = hi_pack2(a.z, a.w);
        hp[2] = hi_pack2(v.x, v.y);
        hp[3] = hi_pack2(v.z, v.w);
        int il = i & 63, kt = c64 >> 3, c = c64 & 7;
        size_t base = ((size_t)(i >> 6) * 8 + kt) * 4096 + il * 64 + ((c ^ (il & 7)) * 8);
        *(uint4*)&xh[base] = *(uint4*)hp;
    } else {
        __shared__ float t[64][65];
        int b2 = b - 17408;                          // head*8 + kt
        int head = b2 >> 3, k0 = (b2 & 7) * 64;
        #pragma unroll
        for (int it = 0; it < 4; ++it) {
            int e = (tid + it * 256) * 4;            // over 64k x 64f
            int kl = e >> 6, f4 = e & 63;
            float4 v = *(const float4*)&Ws[((size_t)head * 512 + k0 + kl) * 64 + f4];
            t[f4 + 0][kl] = v.x; t[f4 + 1][kl] = v.y;
            t[f4 + 2][kl] = v.z; t[f4 + 3][kl] = v.w;
        }
        __syncthreads();
        int f = tid >> 2;
        #pragma unroll
        for (int p = 0; p < 2; ++p) {
            int c = (tid & 3) * 2 + p;
            unsigned hp[4];
            #pragma unroll
            for (int pp = 0; pp < 4; ++pp)
                hp[pp] = hi_pack2(t[f][c * 8 + 2 * pp], t[f][c * 8 + 2 * pp + 1]);
            size_t base = (size_t)b2 * 4096 + f * 64 + ((c ^ (f & 7)) * 8);
            *(uint4*)&wth[base] = *(uint4*)hp;
        }
    }
}

// h = x_hi @ W_hi (single bf16 product), m97-style staging, 4 blk/CU.
// Epilogue emits FRAG-MAJOR h image + per-row softmax factors:
// rL = exp(.8*s1), ebL = {exp(s2), exp(.2*s2)}. grid (8 heads, 64 itiles).
// Frag layout per tile: value h[j=c*8+e][f] at shorts offset
//   (c>>2)*2048 + (f>>4)*512 + ((c&3)*16 + (f&15))*8 + e.
__global__ __launch_bounds__(256) void gemm_fused(const unsigned short* __restrict__ xh,
                                                  const unsigned short* __restrict__ wth,
                                                  const float* __restrict__ As,
                                                  unsigned short* __restrict__ imgh,
                                                  float* __restrict__ rL,
                                                  float2* __restrict__ ebL) {
    __shared__ __align__(16) unsigned short lds[2][2][4096];  // 32 KB: [buf][x,w]
    const int tid = threadIdx.x;
    const int head = blockIdx.x;
    const int itile = blockIdx.y;
    const int i0 = itile * 64;
    const unsigned short* srcs[2] = {xh + (size_t)itile * 8 * 4096,
                                     wth + (size_t)head * 8 * 4096};
    const int lane = tid & 63, wv_ = tid >> 6;
    const int mi = (wv_ & 1) * 32, fi = (wv_ >> 1) * 32;
    const int row = lane & 15, quad = lane >> 4;
    f32x4 acc[2][2] = {};

    #define GSTAGE(buf, kt)                                                                \
        do {                                                                               \
            _Pragma("unroll")                                                              \
            for (int q_ = 0; q_ < 2; ++q_) {                                               \
                const unsigned short* s_ = srcs[q_] + (size_t)(kt) * 4096;                 \
                _Pragma("unroll")                                                          \
                for (int c_ = 0; c_ < 2; ++c_)                                             \
                    __builtin_amdgcn_global_load_lds(                                      \
                        (const __attribute__((address_space(1))) unsigned int*)(s_ + c_ * 2048 + tid * 8), \
                        (__attribute__((address_space(3))) unsigned int*)&lds[buf][q_][c_ * 2048 + tid * 8], \
                        16, 0, 0);                                                         \
            }                                                                              \
        } while (0)

    GSTAGE(0, 0);
    for (int kt = 0; kt < 8; ++kt) {
        __syncthreads();                             // drains loads into buf cur
        const int cur = kt & 1;
        if (kt + 1 < 8) GSTAGE(cur ^ 1, kt + 1);
        #pragma unroll
        for (int ks = 0; ks < 2; ++ks) {
            bf16x8 ah[2], bh[2];
            #pragma unroll
            for (int t = 0; t < 2; ++t) {
                const int m_ = mi + t * 16 + row;
                const int offa = m_ * 64 + (((ks * 4 + quad) ^ (m_ & 7)) * 8);
                ah[t] = *(const bf16x8*)&lds[cur][0][offa];
                const int f_ = fi + t * 16 + row;
                const int offb = f_ * 64 + (((ks * 4 + quad) ^ (f_ & 7)) * 8);
                bh[t] = *(const bf16x8*)&lds[cur][1][offb];
            }
            #pragma unroll
            for (int mt = 0; mt < 2; ++mt)
                #pragma unroll
                for (int nt = 0; nt < 2; ++nt)
                    acc[mt][nt] = __builtin_amdgcn_mfma_f32_16x16x32_bf16(ah[mt], bh[nt], acc[mt][nt], 0, 0, 0);
        }
    }
    #undef GSTAGE
    // ---- fused epilogue ----
    __syncthreads();
    float* ht = (float*)&lds[0][0][0];               // 64 x 68 f32 (17.4 KB <= 32 KB)
    #pragma unroll
    for (int mt = 0; mt < 2; ++mt)
        #pragma unroll
        for (int nt = 0; nt < 2; ++nt)
            #pragma unroll
            for (int r = 0; r < 4; ++r)
                ht[(mi + mt * 16 + quad * 4 + r) * 68 + fi + nt * 16 + row] = acc[mt][nt][r];
    __syncthreads();
    {   // s1/s2 -> row factors: thread t -> row t>>2, seg (t&3)*16
        const int rrow = tid >> 2, seg = (tid & 3) * 16;
        const float* ah = As + head * 128;
        float p1 = 0.f, p2 = 0.f;
        #pragma unroll
        for (int c = 0; c < 16; ++c) {
            float v = ht[rrow * 68 + seg + c];
            p1 += v * ah[seg + c];
            p2 += v * ah[64 + seg + c];
        }
        p1 += __shfl_xor(p1, 1); p1 += __shfl_xor(p1, 2);
        p2 += __shfl_xor(p2, 1); p2 += __shfl_xor(p2, 2);
        if ((tid & 3) == 0) {
            const int gi = i0 + rrow;
            rL[head * GN + gi] = FAST_EXP2(0.8f * p1 * LOG2E);
            float2 e;
            e.x = FAST_EXP2(p2 * LOG2E);
            e.y = FAST_EXP2(0.2f * p2 * LOG2E);
            ebL[head * GN + gi] = e;
        }
    }
    {   // FRAG-MAJOR image emit (hi only)
        const int f = tid >> 2;
        size_t base = ((size_t)head * 64 + itile) * 4096;
        #pragma unroll
        for (int p = 0; p < 2; ++p) {
            int c = (tid & 3) * 2 + p;
            unsigned hp[4];
            #pragma unroll
            for (int pp = 0; pp < 4; ++pp)
                hp[pp] = hi_pack2(ht[(c * 8 + 2 * pp) * 68 + f], ht[(c * 8 + 2 * pp + 1) * 68 + f]);
            size_t off = (size_t)(c >> 2) * 2048 + (size_t)(f >> 4) * 512 +
                         (size_t)((c & 3) * 16 + (f & 15)) * 8;
            *(uint4*)&imgh[base + off] = *(uint4*)hp;
        }
    }
}

// Fused masked-softmax attention, MULTIPLICATIVE weights, BARRIER-FREE:
// w'_ij = max(r_i*B_j, b_j) * adj. NO LDS: bh fragments read directly from
// the frag-major image (1 coalesced dwordx4 per fragment per wave).
// eb(ks0)/adj prefetched 1 tile ahead (regs); bh + eb(ks1) at tile top.
// den = ones-column MFMA on the SAME rounded bf16 weights.
// 256 thr = 4 waves x 16 rows, free-running. grid (64 i-tiles, GNH*NCHUNK or NCHUNK).
template <int NCHUNK>
__global__ __launch_bounds__(256, 4) void attn11(const unsigned short* __restrict__ imgh,
                                                 const float* __restrict__ rg,
                                                 const float2* __restrict__ ebg,
                                                 const unsigned long long* __restrict__ adjb,
                                                 float* __restrict__ pO,
                                                 float* __restrict__ pd) {
    const int tid = threadIdx.x;
    const int lane = tid & 63, wv = tid >> 6;
    const int row = lane & 15, quad = lane >> 4;
    const int head = blockIdx.y / NCHUNK;
    const int chunk = blockIdx.y % NCHUNK;
    const int i0 = blockIdx.x * 64;
    const int jb = chunk * (GN / NCHUNK);
    const int njt = (GN / NCHUNK) / 64;
    const int jt0 = jb >> 6;
    const unsigned short* ih = imgh + (size_t)head * (64 * GN);
    const float2* ebh = ebg + (size_t)head * GN;
    const int gr = i0 + wv * 16 + row;
    const float rv = rg[head * GN + gr];
    const unsigned long long* adjr = adjb + (size_t)gr * 64 + jt0;

    f32x4 acc[4] = {};
    f32x4 accd = {};
    union { unsigned u[4]; bf16x8 v; } ones;
    #pragma unroll
    for (int q = 0; q < 4; ++q) ones.u[q] = 0x3F803F80u;   // bf16 1.0 x8

    // per-lane fragment base: tile base + lane*16 bytes; fragment fr at +fr*1024
    const char* tbl = (const char*)(ih + (size_t)jt0 * 4096) + lane * 16;
    // eb as float4 stream: tile t, ks k, idx p -> ebq[t*32 + k*16 + p]
    const float4* ebq = (const float4*)ebh + (jb >> 1) + quad * 4;

    // pack 8 weights + den-MFMA + 4 PV-MFMA for one ks
    #define KS(WD, KSC, E0, E1, E2, E3, Q0, Q1, Q2, Q3)                                    \
        do {                                                                               \
            const unsigned bits = (unsigned)((WD) >> ((KSC) * 32 + quad * 8)) & 0xFFu;     \
            const float4 ee[4] = {E0, E1, E2, E3};                                         \
            union { unsigned u[4]; bf16x8 v; } wfr;                                        \
            _Pragma("unroll")                                                              \
            for (int p = 0; p < 4; ++p) {                                                  \
                const float4 e = ee[p];              /* {B0, b0, B1, b1} */                \
                const float m0 = (float)((bits >> (2 * p)) & 1u);                          \
                const float m1 = (float)((bits >> (2 * p + 1)) & 1u);                      \
                const float w0 = fmaxf(rv * e.x, e.y) * m0;                                \
                const float w1 = fmaxf(rv * e.z, e.w) * m1;                                \
                wfr.u[p] = hi_pack2(w0, w1);                                               \
            }                                                                              \
            accd = __builtin_amdgcn_mfma_f32_16x16x32_bf16(wfr.v, ones.v, accd, 0, 0, 0);  \
            union { uint4 q; bf16x8 v; } b0u, b1u, b2u, b3u;                               \
            b0u.q = Q0; b1u.q = Q1; b2u.q = Q2; b3u.q = Q3;                                \
            acc[0] = __builtin_amdgcn_mfma_f32_16x16x32_bf16(wfr.v, b0u.v, acc[0], 0, 0, 0); \
            acc[1] = __builtin_amdgcn_mfma_f32_16x16x32_bf16(wfr.v, b1u.v, acc[1], 0, 0, 0); \
            acc[2] = __builtin_amdgcn_mfma_f32_16x16x32_bf16(wfr.v, b2u.v, acc[2], 0, 0, 0); \
            acc[3] = __builtin_amdgcn_mfma_f32_16x16x32_bf16(wfr.v, b3u.v, acc[3], 0, 0, 0); \
        } while (0)

    // prologue: tile-0 ks0 factors + adj word
    float4 n0 = ebq[0], n1 = ebq[1], n2 = ebq[2], n3 = ebq[3];
    unsigned long long wdn = adjr[0];

    #pragma unroll 2
    for (int jt = 0; jt < njt; ++jt) {
        const float4 f0 = n0, f1 = n1, f2 = n2, f3 = n3;
        const unsigned long long wd = wdn;
        // bh fragments for THIS tile (8 coalesced 1KB loads)
        const uint4 q0 = *(const uint4*)(tbl + 0);
        const uint4 q1 = *(const uint4*)(tbl + 1024);
        const uint4 q2 = *(const uint4*)(tbl + 2048);
        const uint4 q3 = *(const uint4*)(tbl + 3072);
        const uint4 q4 = *(const uint4*)(tbl + 4096);
        const uint4 q5 = *(const uint4*)(tbl + 5120);
        const uint4 q6 = *(const uint4*)(tbl + 6144);
        const uint4 q7 = *(const uint4*)(tbl + 7168);
        // ks1 factors for THIS tile (covered by pack-ks0 + 5 MFMA)
        const float4* e1 = ebq + jt * 32 + 16;
        const float4 c0 = e1[0], c1 = e1[1], c2 = e1[2], c3 = e1[3];
        // prefetch NEXT tile ks0 factors + adj
        if (jt + 1 < njt) {
            const float4* e0 = ebq + (jt + 1) * 32;
            n0 = e0[0]; n1 = e0[1]; n2 = e0[2]; n3 = e0[3];
            wdn = adjr[jt + 1];
        }
        KS(wd, 0, f0, f1, f2, f3, q0, q1, q2, q3);
        KS(wd, 1, c0, c1, c2, c3, q4, q5, q6, q7);
        tbl += 8192;
    }
    #undef KS

    float* o = pO + (size_t)blockIdx.y * (GN * 64);
    #pragma unroll
    for (int r = 0; r < 4; ++r) {
        const int grow = i0 + wv * 16 + quad * 4 + r;
        #pragma unroll
        for (int nt = 0; nt < 4; ++nt)
            o[(size_t)grow * 64 + nt * 16 + row] = acc[nt][r];
    }
    // accd: D[i][j] = den_i (cols identical since B==1); C/D row = quad*4+r
    if (row == 0) {
        #pragma unroll
        for (int r = 0; r < 4; ++r)
            pd[blockIdx.y * GN + i0 + wv * 16 + quad * 4 + r] = accd[r];
    }
}

// Fused zred + l2prep, 16 rows/block (256 blocks): combine 2-chunk L1
// partials -> z (LDS) -> h2 = z @ W_out -> row factors + FRAG-MAJOR image.
__global__ __launch_bounds__(256) void mid(const float* __restrict__ pO,
                                           const float* __restrict__ pd,
                                           const float* __restrict__ Wo,
                                           const float* __restrict__ ao,
                                           unsigned short* __restrict__ img2h,
                                           float* __restrict__ rbL,
                                           float2* __restrict__ eb2L) {
    __shared__ __align__(16) float zt[16][68];
    __shared__ float Wl[64 * 57];
    __shared__ float invd[8][16];
    const int tid = threadIdx.x;
    const int i0 = blockIdx.x * 16;
    for (int idx = tid; idx < 64 * 56; idx += 256) {
        int k = idx / 56, c = idx - k * 56;
        Wl[k * 57 + c] = Wo[idx];
    }
    if (tid < 128) {
        int hd = tid >> 4, r = tid & 15;
        invd[hd][r] = 1.f / (pd[(2 * hd) * GN + i0 + r] + pd[(2 * hd + 1) * GN + i0 + r]);
    }
    __syncthreads();
    #pragma unroll
    for (int it = 0; it < 4; ++it) {                 // z fill: 16x64 elems
        int e = it * 256 + tid;
        int r = e >> 6, f = e & 63;
        size_t base = (size_t)(i0 + r) * 64 + f;
        float s = 0.f;
        #pragma unroll
        for (int hd = 0; hd < GNH; ++hd) {
            float o = pO[(size_t)(2 * hd) * (GN * 64) + base] +
                      pO[(size_t)(2 * hd + 1) * (GN * 64) + base];
            float v = o * invd[hd][r];
            s += v > 0.f ? v : FAST_EXP2(v * LOG2E) - 1.f;
        }
        zt[r][f] = s * 0.125f;
    }
    __syncthreads();
    const int rrow = tid >> 4, cseg = (tid & 15) * 4;
    float hreg[4] = {0.f, 0.f, 0.f, 0.f};
    for (int k0 = 0; k0 < 64; k0 += 4) {
        float4 zv = *(const float4*)&zt[rrow][k0];
        #pragma unroll
        for (int c = 0; c < 4; ++c) {
            int col = cseg + c;
            if (col < 56)
                hreg[c] += zv.x * Wl[k0 * 57 + col] + zv.y * Wl[(k0 + 1) * 57 + col] +
                           zv.z * Wl[(k0 + 2) * 57 + col] + zv.w * Wl[(k0 + 3) * 57 + col];
        }
    }
    {   // row factors for L2 attention
        float p1 = 0.f, p2 = 0.f;
        #pragma unroll
        for (int c = 0; c < 4; ++c) {
            int col = cseg + c;
            if (col < 56) {
                p1 += hreg[c] * ao[col];
                p2 += hreg[c] * ao[56 + col];
            }
        }
        p1 += __shfl_xor(p1, 1); p1 += __shfl_xor(p1, 2);
        p1 += __shfl_xor(p1, 4); p1 += __shfl_xor(p1, 8);
        p2 += __shfl_xor(p2, 1); p2 += __shfl_xor(p2, 2);
        p2 += __shfl_xor(p2, 4); p2 += __shfl_xor(p2, 8);
        if ((tid & 15) == 0) {
            rbL[i0 + rrow] = FAST_EXP2(0.8f * p1 * LOG2E);
            float2 e;
            e.x = FAST_EXP2(p2 * LOG2E);
            e.y = FAST_EXP2(0.2f * p2 * LOG2E);
            eb2L[i0 + rrow] = e;
        }
    }
    __syncthreads();
    #pragma unroll
    for (int c = 0; c < 4; ++c) zt[rrow][cseg + c] = (cseg + c < 56) ? hreg[c] : 0.f;
    __syncthreads();
    if (tid < 128) {                                 // FRAG-MAJOR img emit
        const int jt = i0 >> 6;
        const int cbase = (i0 & 63) >> 3;
        const int f = tid >> 1, c = cbase + (tid & 1);
        const int lr = (tid & 1) * 8;
        unsigned hp[4];
        #pragma unroll
        for (int pp = 0; pp < 4; ++pp)
            hp[pp] = hi_pack2(zt[lr + 2 * pp][f], zt[lr + 2 * pp + 1][f]);
        size_t base = (size_t)jt * 4096 + (size_t)(c >> 2) * 2048 +
                      (size_t)(f >> 4) * 512 + (size_t)((c & 3) * 16 + (f & 15)) * 8;
        *(uint4*)&img2h[base] = *(uint4*)hp;
    }
}

// combine 16 j-chunk partials, /denom, elu, softmax(56) -> out
__global__ __launch_bounds__(256) void fink2(const float* __restrict__ pO,
                                             const float* __restrict__ pd,
                                             float* __restrict__ out) {
    const int lane = threadIdx.x & 63;
    const int w = threadIdx.x >> 6;
    const int i = blockIdx.x * 4 + w;
    float o = 0.f, d = 0.f;
    #pragma unroll
    for (int c = 0; c < 16; ++c) d += pd[c * GN + i];
    if (lane < 56) {
        #pragma unroll
        for (int c = 0; c < 16; ++c) o += pO[(size_t)c * (GN * 64) + (size_t)i * 64 + lane];
    }
    float v = -1e30f;
    if (lane < 56) {
        float t = o / d;
        v = t > 0.f ? t : expm1f(t);
    }
    float m = v;
    #pragma unroll
    for (int off = 32; off; off >>= 1) m = fmaxf(m, __shfl_down(m, off));
    m = __shfl(m, 0);
    float p = (lane < 56) ? __expf(v - m) : 0.f;
    float s = p;
    #pragma unroll
    for (int off = 32; off; off >>= 1) s += __shfl_down(s, off);
    s = __shfl(s, 0);
    if (lane < 56) out[(size_t)i * 56 + lane] = p / s;
}

extern "C" void kernel_launch(void* const* d_in, const int* in_sizes, int n_in,
                              void* d_out, int out_size, void* d_ws, size_t ws_size,
                              hipStream_t stream) {
    const float* x    = (const float*)d_in[0];
    const int*   adj  = (const int*)d_in[1];
    const float* Ws   = (const float*)d_in[2];
    const float* As   = (const float*)d_in[3];
    const float* Wo   = (const float*)d_in[4];
    const float* ao   = (const float*)d_in[5];
    float* out = (float*)d_out;

    char* ws = (char*)d_ws;
    unsigned long long* adjb = (unsigned long long*)(ws + 0);           // [0, 2097152)
    unsigned short* img1h = (unsigned short*)(ws + 2097152);            // [2097152, 6291456)
    float* pO    = (float*)(ws + 6291456);                              // [6291456, 23068672) 16 slices
    unsigned short* x_hi = (unsigned short*)(ws + 6291456);             // alias pO (pre-gemm only)
    float* pd    = (float*)(ws + 23068672);                             // [23068672, 23330816)
    float* rL    = (float*)(ws + 23330816);                             // [23330816, 23461888)
    float2* ebL  = (float2*)(ws + 23461888);                            // [23461888, 23724032)
    float* rbL   = (float*)(ws + 23724032);                             // [23724032, 23740416)
    float2* eb2L = (float2*)(ws + 23740416);                            // [23740416, 23773184)
    unsigned short* img2h = (unsigned short*)(ws + 23773184);           // [23773184, 24297472)
    unsigned short* WT_hi = (unsigned short*)(ws + 24297472);           // [24297472, 24821760)
    // total ~24.82 MB, no overlaps

    prep<<<17472, 256, 0, stream>>>(adj, x, Ws, adjb, x_hi, WT_hi);
    gemm_fused<<<dim3(8, 64), 256, 0, stream>>>(x_hi, WT_hi, As, img1h, rL, ebL);
    attn11<2><<<dim3(64, 16), 256, 0, stream>>>(img1h, rL, ebL, adjb, pO, pd);
    mid<<<256, 256, 0, stream>>>(pO, pd, Wo, ao, img2h, rbL, eb2L);
    attn11<16><<<dim3(64, 16), 256, 0, stream>>>(img2h, rbL, eb2L, adjb, pO, pd);
    fink2<<<1024, 256, 0, stream>>>(pO, pd, out);
}

// Round 9
// 185.233 us; speedup vs baseline: 1.2489x; 1.2489x over previous
//
#include <hip/hip_runtime.h>
#include <hip/hip_bf16.h>
#include <math.h>

// GAT forward, N=4096, nfeat=512, nhid=64, nheads=8, nout=56, f32 in/out.
// R24 = R23 with the cvt_pkrtz RETURN-TYPE FIX (R23 failed to compile:
// __builtin_amdgcn_cvt_pkrtz returns __fp16x2, not _Float16x2; receive it
// into a __fp16-vector union member -- same 32-bit layout, pure bitcast).
// R22 theory vs R20 (R20: 205.6us attn 59.7; R21 barrier-free REGRESSED
// to 87.4 by 4x-ing L2/L3 traffic -- LDS staging is load-bearing):
// attn VALU time is a FIXED ~30us across R15-R21 (VALUBusy% x dur
// invariant). Structure tuning can't cut it; the weight math can:
// switch the WHOLE pipeline bf16 -> FP16 (all values in [e^-4, ~25];
// fp16 has 3 more mantissa bits -> accuracy improves):
//  - eb factors stored as PACKED fp16 pairs {B_{2j},B_{2j+1}},{b_...}
//    (uint2/j-pair). Scalar load bytes in attn HALVE.
//  - attn weight pack: v_pk_mul_f16 + v_pk_max_f16 + sign-bit mask
//    (2x bfe + v_perm + and) ~= 7 VALU/pair vs 14; no explicit rounding
//    (pk ops are RNE). den ones-MFMA on the same packed values.
//  - images (x, W^T, h, z) emitted as fp16 via v_cvt_pkrtz; MFMA ->
//    _f16 variants (same rate, same fragment/C-D layout -> R20's proven
//    swizzle & skeleton byte-identical otherwise).
// prep/gemm/mid/fink2 structure and workspace identical to R20.

#define GN 4096
#define GNH 8
#define LOG2E 1.4426950408889634f

typedef _Float16 f16x8 __attribute__((ext_vector_type(8)));
typedef _Float16 f16x2 __attribute__((ext_vector_type(2)));
typedef __fp16 fp16x2_raw __attribute__((ext_vector_type(2)));
typedef float f32x4 __attribute__((ext_vector_type(4)));

#if defined(__has_builtin)
#if __has_builtin(__builtin_amdgcn_exp2f)
#define FAST_EXP2(x) __builtin_amdgcn_exp2f(x)
#endif
#if __has_builtin(__builtin_amdgcn_perm)
#define MASK_PERM(h, l) __builtin_amdgcn_perm((h), (l), 0x05040100u)
#endif
#if __has_builtin(__builtin_amdgcn_cvt_pkrtz)
#define HAVE_PKRTZ 1
#endif
#endif
#ifndef FAST_EXP2
#define FAST_EXP2(x) __expf((x)*0.6931471805599453f)
#endif
#ifndef MASK_PERM
#define MASK_PERM(h, l) (((h) & 0xFFFF0000u) | ((l) & 0xFFFFu))
#endif

// pack two floats to fp16 pair (a in low 16, b in high 16)
__device__ inline unsigned pk_f16(float a, float b) {
#ifdef HAVE_PKRTZ
    union { fp16x2_raw h; unsigned u; } r;
    r.h = __builtin_amdgcn_cvt_pkrtz(a, b);
    return r.u;
#else
    union { _Float16 h; unsigned short s; } x, y;
    x.h = (_Float16)a; y.h = (_Float16)b;
    return (unsigned)x.s | ((unsigned)y.s << 16);
#endif
}

// Fused prep:
//  [0,16384)      pack_adj  (bitmask)
//  [16384,17408)  conv_x    -> swizzled x image (fp16), tiles [itile*8+kt]
//  [17408,17472)  conv_wt   -> swizzled W^T image (fp16), tiles [head*8+kt]
// Image unit (m, c) at shorts offset m*64 + ((c^(m&7))*8), elems k = c*8+q.
__global__ __launch_bounds__(256) void prep(const int* __restrict__ adj,
                                            const float* __restrict__ x,
                                            const float* __restrict__ Ws,
                                            unsigned long long* __restrict__ adjb,
                                            unsigned short* __restrict__ xh,
                                            unsigned short* __restrict__ wth) {
    const int b = blockIdx.x;
    const int tid = threadIdx.x;
    if (b < 16384) {
        const int wv = tid >> 6, lane = tid & 63;
        const size_t ebase = ((size_t)b * 4 + wv) * 256;
        unsigned long long m[4];
        #pragma unroll
        for (int e = 0; e < 4; ++e)
            m[e] = __ballot(adj[ebase + e * 64 + lane] > 0);
        if (lane == 0) {
            #pragma unroll
            for (int e = 0; e < 4; ++e) adjb[(ebase >> 6) + e] = m[e];
        }
    } else if (b < 17408) {
        int gid = (b - 16384) * 256 + tid;           // over 4096 rows x 64 units
        int i = gid >> 6, c64 = gid & 63;
        const float* xp = x + (size_t)i * 512 + c64 * 8;
        float4 a = *(const float4*)xp;
        float4 v = *(const float4*)(xp + 4);
        unsigned hp[4];
        hp[0] = pk_f16(a.x, a.y);
        hp[1] = pk_f16(a.z, a.w);
        hp[2] = pk_f16(v.x, v.y);
        hp[3] = pk_f16(v.z, v.w);
        int il = i & 63, kt = c64 >> 3, c = c64 & 7;
        size_t base = ((size_t)(i >> 6) * 8 + kt) * 4096 + il * 64 + ((c ^ (il & 7)) * 8);
        *(uint4*)&xh[base] = *(uint4*)hp;
    } else {
        __shared__ float t[64][65];
        int b2 = b - 17408;                          // head*8 + kt
        int head = b2 >> 3, k0 = (b2 & 7) * 64;
        #pragma unroll
        for (int it = 0; it < 4; ++it) {
            int e = (tid + it * 256) * 4;            // over 64k x 64f
            int kl = e >> 6, f4 = e & 63;
            float4 v = *(const float4*)&Ws[((size_t)head * 512 + k0 + kl) * 64 + f4];
            t[f4 + 0][kl] = v.x; t[f4 + 1][kl] = v.y;
            t[f4 + 2][kl] = v.z; t[f4 + 3][kl] = v.w;
        }
        __syncthreads();
        int f = tid >> 2;
        #pragma unroll
        for (int p = 0; p < 2; ++p) {
            int c = (tid & 3) * 2 + p;
            unsigned hp[4];
            #pragma unroll
            for (int pp = 0; pp < 4; ++pp)
                hp[pp] = pk_f16(t[f][c * 8 + 2 * pp], t[f][c * 8 + 2 * pp + 1]);
            size_t base = (size_t)b2 * 4096 + f * 64 + ((c ^ (f & 7)) * 8);
            *(uint4*)&wth[base] = *(uint4*)hp;
        }
    }
}

// h = x @ W (single fp16 product), m97-style staging, 4 blk/CU.
// Epilogue emits fp16 swizzled h image + per-row softmax factors:
// rL = exp(.8*s1) f32; ebL = packed fp16 pairs {B_{2j},B_{2j+1}},{b_..}.
// grid (8 heads, 64 itiles).
__global__ __launch_bounds__(256) void gemm_fused(const unsigned short* __restrict__ xh,
                                                  const unsigned short* __restrict__ wth,
                                                  const float* __restrict__ As,
                                                  unsigned short* __restrict__ imgh,
                                                  float* __restrict__ rL,
                                                  uint2* __restrict__ ebL) {
    __shared__ __align__(16) unsigned short lds[2][2][4096];  // 32 KB: [buf][x,w]
    const int tid = threadIdx.x;
    const int head = blockIdx.x;
    const int itile = blockIdx.y;
    const int i0 = itile * 64;
    const unsigned short* srcs[2] = {xh + (size_t)itile * 8 * 4096,
                                     wth + (size_t)head * 8 * 4096};
    const int lane = tid & 63, wv_ = tid >> 6;
    const int mi = (wv_ & 1) * 32, fi = (wv_ >> 1) * 32;
    const int row = lane & 15, quad = lane >> 4;
    f32x4 acc[2][2] = {};

    #define GSTAGE(buf, kt)                                                                \
        do {                                                                               \
            _Pragma("unroll")                                                              \
            for (int q_ = 0; q_ < 2; ++q_) {                                               \
                const unsigned short* s_ = srcs[q_] + (size_t)(kt) * 4096;                 \
                _Pragma("unroll")                                                          \
                for (int c_ = 0; c_ < 2; ++c_)                                             \
                    __builtin_amdgcn_global_load_lds(                                      \
                        (const __attribute__((address_space(1))) unsigned int*)(s_ + c_ * 2048 + tid * 8), \
                        (__attribute__((address_space(3))) unsigned int*)&lds[buf][q_][c_ * 2048 + tid * 8], \
                        16, 0, 0);                                                         \
            }                                                                              \
        } while (0)

    GSTAGE(0, 0);
    for (int kt = 0; kt < 8; ++kt) {
        __syncthreads();                             // drains loads into buf cur
        const int cur = kt & 1;
        if (kt + 1 < 8) GSTAGE(cur ^ 1, kt + 1);
        #pragma unroll
        for (int ks = 0; ks < 2; ++ks) {
            f16x8 ah[2], bh[2];
            #pragma unroll
            for (int t = 0; t < 2; ++t) {
                const int m_ = mi + t * 16 + row;
                const int offa = m_ * 64 + (((ks * 4 + quad) ^ (m_ & 7)) * 8);
                ah[t] = *(const f16x8*)&lds[cur][0][offa];
                const int f_ = fi + t * 16 + row;
                const int offb = f_ * 64 + (((ks * 4 + quad) ^ (f_ & 7)) * 8);
                bh[t] = *(const f16x8*)&lds[cur][1][offb];
            }
            #pragma unroll
            for (int mt = 0; mt < 2; ++mt)
                #pragma unroll
                for (int nt = 0; nt < 2; ++nt)
                    acc[mt][nt] = __builtin_amdgcn_mfma_f32_16x16x32_f16(ah[mt], bh[nt], acc[mt][nt], 0, 0, 0);
        }
    }
    #undef GSTAGE
    // ---- fused epilogue ----
    __syncthreads();
    float* ht = (float*)&lds[0][0][0];               // 64 x 68 f32 (17.4 KB <= 32 KB)
    #pragma unroll
    for (int mt = 0; mt < 2; ++mt)
        #pragma unroll
        for (int nt = 0; nt < 2; ++nt)
            #pragma unroll
            for (int r = 0; r < 4; ++r)
                ht[(mi + mt * 16 + quad * 4 + r) * 68 + fi + nt * 16 + row] = acc[mt][nt][r];
    __syncthreads();
    {   // s1/s2 -> row factors: thread t -> row t>>2, seg (t&3)*16
        const int rrow = tid >> 2, seg = (tid & 3) * 16;
        const float* ah = As + head * 128;
        float p1 = 0.f, p2 = 0.f;
        #pragma unroll
        for (int c = 0; c < 16; ++c) {
            float v = ht[rrow * 68 + seg + c];
            p1 += v * ah[seg + c];
            p2 += v * ah[64 + seg + c];
        }
        p1 += __shfl_xor(p1, 1); p1 += __shfl_xor(p1, 2);
        p2 += __shfl_xor(p2, 1); p2 += __shfl_xor(p2, 2);
        // all lanes now hold full p1,p2 for row rrow
        const float r_ = FAST_EXP2(0.8f * p1 * LOG2E);
        const float B_ = FAST_EXP2(p2 * LOG2E);
        const float b_ = FAST_EXP2(0.2f * p2 * LOG2E);
        const float Bo = __shfl_xor(B_, 4);          // row rrow^1's B
        const float bo = __shfl_xor(b_, 4);
        const int gi = i0 + rrow;
        if ((tid & 3) == 0) rL[head * GN + gi] = r_;
        if ((tid & 7) == 0) {                        // even rrow writes the pair
            uint2 e;
            e.x = pk_f16(B_, Bo);
            e.y = pk_f16(b_, bo);
            ebL[head * (GN / 2) + (gi >> 1)] = e;
        }
    }
    {   // swizzled image emit (fp16)
        const int f = tid >> 2;
        size_t base = ((size_t)head * 64 + itile) * 4096 + (size_t)f * 64;
        #pragma unroll
        for (int p = 0; p < 2; ++p) {
            int c = (tid & 3) * 2 + p;
            unsigned hp[4];
            #pragma unroll
            for (int pp = 0; pp < 4; ++pp)
                hp[pp] = pk_f16(ht[(c * 8 + 2 * pp) * 68 + f], ht[(c * 8 + 2 * pp + 1) * 68 + f]);
            int off = (c ^ (f & 7)) * 8;
            *(uint4*)&imgh[base + off] = *(uint4*)hp;
        }
    }
}

// Fused masked-softmax attention, MULTIPLICATIVE fp16-packed weights:
// w'_pair = pk_max(pk_mul(rv2, B2), b2) & signext-bit-mask. No rounding
// step (pk ops RNE); den = ones-MFMA on the SAME packed values.
// R20 skeleton: 2 j-tiles per barrier phase, hb = 2 bufs x 2 tiles = 32 KB,
// scalar prefetch rotates 1 tile ahead. 256 thr = 4 waves x 16 rows.
// grid (64 i-tiles, GNH*NCHUNK or NCHUNK).
template <int NCHUNK>
__global__ __launch_bounds__(256, 4) void attn12(const unsigned short* __restrict__ imgh,
                                                 const float* __restrict__ rg,
                                                 const uint2* __restrict__ ebg,
                                                 const unsigned long long* __restrict__ adjb,
                                                 float* __restrict__ pO,
                                                 float* __restrict__ pd) {
    __shared__ __align__(16) unsigned short hb[2][8192];   // [buf][2 tiles, swizzled]
    const int tid = threadIdx.x;
    const int lane = tid & 63, wv = tid >> 6;
    const int row = lane & 15, quad = lane >> 4;
    const int head = blockIdx.y / NCHUNK;
    const int chunk = blockIdx.y % NCHUNK;
    const int i0 = blockIdx.x * 64;
    const int jb = chunk * (GN / NCHUNK);
    const int njt = (GN / NCHUNK) / 64;
    const int njp = njt >> 1;                        // 2 tiles per phase
    const int jt0 = jb >> 6;
    const unsigned short* ih = imgh + (size_t)head * (64 * GN);
    const int gr = i0 + wv * 16 + row;
    const float rv = rg[head * GN + gr];
    const unsigned long long* adjr = adjb + (size_t)gr * 64 + jt0;
    // eb uint4 stream: tile t, ks k, quad q -> ebq4[t*16 + k*8 + q*2 + {0,1}]
    const uint4* ebq4 = (const uint4*)(ebg + (size_t)head * (GN / 2)) + (jb >> 2) + quad * 2;

    const _Float16 rh = (_Float16)rv;
    const f16x2 rv2 = {rh, rh};

    f32x4 acc[4] = {};
    f32x4 accd = {};
    union { unsigned u[4]; f16x8 v; } ones;
    #pragma unroll
    for (int q = 0; q < 4; ++q) ones.u[q] = 0x3C003C00u;   // fp16 1.0 x8

    // stage tiles T and T+1 (contiguous 16 KB in imgh) into hb[buf]
    #define STAGE2(buf, T)                                                                 \
        do {                                                                               \
            const unsigned short* gh_ = ih + (size_t)(T) * 4096;                           \
            _Pragma("unroll")                                                              \
            for (int c_ = 0; c_ < 4; ++c_)                                                 \
                __builtin_amdgcn_global_load_lds(                                          \
                    (const __attribute__((address_space(1))) unsigned int*)(gh_ + c_ * 2048 + tid * 8), \
                    (__attribute__((address_space(3))) unsigned int*)&hb[buf][c_ * 2048 + tid * 8],     \
                    16, 0, 0);                                                             \
        } while (0)

    // one j-tile: pack 16 fp16 weights + den-MFMA + 2x4 PV-MFMA vs hb half
    #define CTILE(cur, half, WD, A0, A1, B0, B1)                                           \
        do {                                                                               \
            _Pragma("unroll")                                                              \
            for (int ks = 0; ks < 2; ++ks) {                                               \
                const unsigned bits = (unsigned)((WD) >> (ks * 32 + quad * 8)) & 0xFFu;    \
                const uint4 ua = ks ? (B0) : (A0);                                         \
                const uint4 ub = ks ? (B1) : (A1);                                         \
                const unsigned Bw[4] = {ua.x, ua.z, ub.x, ub.z};                           \
                const unsigned bw[4] = {ua.y, ua.w, ub.y, ub.w};                           \
                union { unsigned u[4]; f16x8 v; } wfr;                                     \
                _Pragma("unroll")                                                          \
                for (int p = 0; p < 4; ++p) {                                              \
                    const unsigned lo = (unsigned)(((int)(bits << (31 - 2 * p))) >> 31);   \
                    const unsigned hi = (unsigned)(((int)(bits << (30 - 2 * p))) >> 31);   \
                    const unsigned msk = MASK_PERM(hi, lo);                                \
                    union { unsigned u; f16x2 h; } B2, b2, w;                              \
                    B2.u = Bw[p]; b2.u = bw[p];                                            \
                    w.h = __builtin_elementwise_max(rv2 * B2.h, b2.h);                     \
                    wfr.u[p] = w.u & msk;                                                  \
                }                                                                          \
                accd = __builtin_amdgcn_mfma_f32_16x16x32_f16(wfr.v, ones.v, accd, 0, 0, 0); \
                _Pragma("unroll")                                                          \
                for (int nt = 0; nt < 4; ++nt) {                                           \
                    const int f = nt * 16 + row;                                           \
                    const int off = (half) * 4096 + f * 64 + (((ks * 4 + quad) ^ (f & 7)) * 8); \
                    f16x8 bh = *(const f16x8*)&hb[cur][off];                               \
                    acc[nt] = __builtin_amdgcn_mfma_f32_16x16x32_f16(wfr.v, bh, acc[nt], 0, 0, 0); \
                }                                                                          \
            }                                                                              \
        } while (0)

    STAGE2(0, jt0);
    // ---- prologue prefetch of tile 0 scalars (covered by first barrier) ----
    unsigned long long wdn = adjr[0];
    uint4 nA0 = ebq4[0], nA1 = ebq4[1], nB0 = ebq4[8], nB1 = ebq4[9];

    for (int ph = 0; ph < njp; ++ph) {
        __syncthreads();                             // drains stage+scalars for this phase
        const int cur = ph & 1;
        if (ph + 1 < njp) STAGE2(cur ^ 1, jt0 + 2 * (ph + 1));
        // ---- tile A = 2*ph ----
        {
            const unsigned long long wd = wdn;
            const uint4 a0 = nA0, a1 = nA1, b0 = nB0, b1 = nB1;
            {   // prefetch tile 2*ph+1 scalars (always exists)
                const int tn = 2 * ph + 1;
                wdn = adjr[tn];
                nA0 = ebq4[tn * 16];     nA1 = ebq4[tn * 16 + 1];
                nB0 = ebq4[tn * 16 + 8]; nB1 = ebq4[tn * 16 + 9];
            }
            CTILE(cur, 0, wd, a0, a1, b0, b1);
        }
        // ---- tile B = 2*ph+1 ----
        {
            const unsigned long long wd = wdn;
            const uint4 a0 = nA0, a1 = nA1, b0 = nB0, b1 = nB1;
            if (ph + 1 < njp) {                      // prefetch first tile of next phase
                const int tn = 2 * ph + 2;
                wdn = adjr[tn];
                nA0 = ebq4[tn * 16];     nA1 = ebq4[tn * 16 + 1];
                nB0 = ebq4[tn * 16 + 8]; nB1 = ebq4[tn * 16 + 9];
            }
            CTILE(cur, 1, wd, a0, a1, b0, b1);
        }
    }
    #undef STAGE2
    #undef CTILE

    float* o = pO + (size_t)blockIdx.y * (GN * 64);
    #pragma unroll
    for (int r = 0; r < 4; ++r) {
        const int grow = i0 + wv * 16 + quad * 4 + r;
        #pragma unroll
        for (int nt = 0; nt < 4; ++nt)
            o[(size_t)grow * 64 + nt * 16 + row] = acc[nt][r];
    }
    // accd: D[i][j] = den_i (cols identical since B==1); C/D row = quad*4+r
    if (row == 0) {
        #pragma unroll
        for (int r = 0; r < 4; ++r)
            pd[blockIdx.y * GN + i0 + wv * 16 + quad * 4 + r] = accd[r];
    }
}

// Fused zred + l2prep, 16 rows/block (256 blocks): combine 2-chunk L1
// partials -> z (LDS) -> h2 = z @ W_out -> row factors + fp16 image.
__global__ __launch_bounds__(256) void mid(const float* __restrict__ pO,
                                           const float* __restrict__ pd,
                                           const float* __restrict__ Wo,
                                           const float* __restrict__ ao,
                                           unsigned short* __restrict__ img2h,
                                           float* __restrict__ rbL,
                                           uint2* __restrict__ eb2L) {
    __shared__ __align__(16) float zt[16][68];
    __shared__ float Wl[64 * 57];
    __shared__ float invd[8][16];
    const int tid = threadIdx.x;
    const int i0 = blockIdx.x * 16;
    for (int idx = tid; idx < 64 * 56; idx += 256) {
        int k = idx / 56, c = idx - k * 56;
        Wl[k * 57 + c] = Wo[idx];
    }
    if (tid < 128) {
        int hd = tid >> 4, r = tid & 15;
        invd[hd][r] = 1.f / (pd[(2 * hd) * GN + i0 + r] + pd[(2 * hd + 1) * GN + i0 + r]);
    }
    __syncthreads();
    #pragma unroll
    for (int it = 0; it < 4; ++it) {                 // z fill: 16x64 elems
        int e = it * 256 + tid;
        int r = e >> 6, f = e & 63;
        size_t base = (size_t)(i0 + r) * 64 + f;
        float s = 0.f;
        #pragma unroll
        for (int hd = 0; hd < GNH; ++hd) {
            float o = pO[(size_t)(2 * hd) * (GN * 64) + base] +
                      pO[(size_t)(2 * hd + 1) * (GN * 64) + base];
            float v = o * invd[hd][r];
            s += v > 0.f ? v : FAST_EXP2(v * LOG2E) - 1.f;
        }
        zt[r][f] = s * 0.125f;
    }
    __syncthreads();
    const int rrow = tid >> 4, cseg = (tid & 15) * 4;
    float hreg[4] = {0.f, 0.f, 0.f, 0.f};
    for (int k0 = 0; k0 < 64; k0 += 4) {
        float4 zv = *(const float4*)&zt[rrow][k0];
        #pragma unroll
        for (int c = 0; c < 4; ++c) {
            int col = cseg + c;
            if (col < 56)
                hreg[c] += zv.x * Wl[k0 * 57 + col] + zv.y * Wl[(k0 + 1) * 57 + col] +
                           zv.z * Wl[(k0 + 2) * 57 + col] + zv.w * Wl[(k0 + 3) * 57 + col];
        }
    }
    {   // row factors for L2 attention (packed fp16 pairs)
        float p1 = 0.f, p2 = 0.f;
        #pragma unroll
        for (int c = 0; c < 4; ++c) {
            int col = cseg + c;
            if (col < 56) {
                p1 += hreg[c] * ao[col];
                p2 += hreg[c] * ao[56 + col];
            }
        }
        p1 += __shfl_xor(p1, 1); p1 += __shfl_xor(p1, 2);
        p1 += __shfl_xor(p1, 4); p1 += __shfl_xor(p1, 8);
        p2 += __shfl_xor(p2, 1); p2 += __shfl_xor(p2, 2);
        p2 += __shfl_xor(p2, 4); p2 += __shfl_xor(p2, 8);
        // all lanes hold full p1,p2 for row rrow = tid>>4
        const float r_ = FAST_EXP2(0.8f * p1 * LOG2E);
        const float B_ = FAST_EXP2(p2 * LOG2E);
        const float b_ = FAST_EXP2(0.2f * p2 * LOG2E);
        const float Bo = __shfl_xor(B_, 16);         // row rrow^1's B
        const float bo = __shfl_xor(b_, 16);
        if ((tid & 15) == 0) rbL[i0 + rrow] = r_;
        if ((tid & 31) == 0) {                       // even rrow writes the pair
            uint2 e;
            e.x = pk_f16(B_, Bo);
            e.y = pk_f16(b_, bo);
            eb2L[(i0 + rrow) >> 1] = e;
        }
    }
    __syncthreads();
    #pragma unroll
    for (int c = 0; c < 4; ++c) zt[rrow][cseg + c] = (cseg + c < 56) ? hreg[c] : 0.f;
    __syncthreads();
    if (tid < 128) {                                 // img emit: 64 f x 2 c-units (fp16)
        const int jt = i0 >> 6;
        const int cbase = (i0 & 63) >> 3;
        const int f = tid >> 1, c = cbase + (tid & 1);
        const int lr = (tid & 1) * 8;
        unsigned hp[4];
        #pragma unroll
        for (int pp = 0; pp < 4; ++pp)
            hp[pp] = pk_f16(zt[lr + 2 * pp][f], zt[lr + 2 * pp + 1][f]);
        size_t base = (size_t)jt * 4096 + f * 64 + ((c ^ (f & 7)) * 8);
        *(uint4*)&img2h[base] = *(uint4*)hp;
    }
}

// combine 16 j-chunk partials, /denom, elu, softmax(56) -> out
__global__ __launch_bounds__(256) void fink2(const float* __restrict__ pO,
                                             const float* __restrict__ pd,
                                             float* __restrict__ out) {
    const int lane = threadIdx.x & 63;
    const int w = threadIdx.x >> 6;
    const int i = blockIdx.x * 4 + w;
    float o = 0.f, d = 0.f;
    #pragma unroll
    for (int c = 0; c < 16; ++c) d += pd[c * GN + i];
    if (lane < 56) {
        #pragma unroll
        for (int c = 0; c < 16; ++c) o += pO[(size_t)c * (GN * 64) + (size_t)i * 64 + lane];
    }
    float v = -1e30f;
    if (lane < 56) {
        float t = o / d;
        v = t > 0.f ? t : expm1f(t);
    }
    float m = v;
    #pragma unroll
    for (int off = 32; off; off >>= 1) m = fmaxf(m, __shfl_down(m, off));
    m = __shfl(m, 0);
    float p = (lane < 56) ? __expf(v - m) : 0.f;
    float s = p;
    #pragma unroll
    for (int off = 32; off; off >>= 1) s += __shfl_down(s, off);
    s = __shfl(s, 0);
    if (lane < 56) out[(size_t)i * 56 + lane] = p / s;
}

extern "C" void kernel_launch(void* const* d_in, const int* in_sizes, int n_in,
                              void* d_out, int out_size, void* d_ws, size_t ws_size,
                              hipStream_t stream) {
    const float* x    = (const float*)d_in[0];
    const int*   adj  = (const int*)d_in[1];
    const float* Ws   = (const float*)d_in[2];
    const float* As   = (const float*)d_in[3];
    const float* Wo   = (const float*)d_in[4];
    const float* ao   = (const float*)d_in[5];
    float* out = (float*)d_out;

    char* ws = (char*)d_ws;
    unsigned long long* adjb = (unsigned long long*)(ws + 0);           // [0, 2097152)
    unsigned short* img1h = (unsigned short*)(ws + 2097152);            // [2097152, 6291456)
    float* pO    = (float*)(ws + 6291456);                              // [6291456, 23068672) 16 slices
    unsigned short* x_hi = (unsigned short*)(ws + 6291456);             // alias pO (pre-gemm only)
    float* pd    = (float*)(ws + 23068672);                             // [23068672, 23330816)
    float* rL    = (float*)(ws + 23330816);                             // [23330816, 23461888)
    uint2* ebL   = (uint2*)(ws + 23461888);                             // [23461888, 23724032) 8B/j-pair*2048*8
    float* rbL   = (float*)(ws + 23724032);                             // [23724032, 23740416)
    uint2* eb2L  = (uint2*)(ws + 23740416);                             // [23740416, 23756800) 2048*8B
    unsigned short* img2h = (unsigned short*)(ws + 23773184);           // [23773184, 24297472)
    unsigned short* WT_hi = (unsigned short*)(ws + 24297472);           // [24297472, 24821760)
    // total ~24.82 MB, no overlaps (ebL/eb2L shrank within their old slots)

    prep<<<17472, 256, 0, stream>>>(adj, x, Ws, adjb, x_hi, WT_hi);
    gemm_fused<<<dim3(8, 64), 256, 0, stream>>>(x_hi, WT_hi, As, img1h, rL, ebL);
    attn12<2><<<dim3(64, 16), 256, 0, stream>>>(img1h, rL, ebL, adjb, pO, pd);
    mid<<<256, 256, 0, stream>>>(pO, pd, Wo, ao, img2h, rbL, eb2L);
    attn12<16><<<dim3(64, 16), 256, 0, stream>>>(img2h, rbL, eb2L, adjb, pO, pd);
    fink2<<<1024, 256, 0, stream>>>(pO, pd, out);
}